// Round 5
// baseline (448.085 us; speedup 1.0000x reference)
//
#include <hip/hip_runtime.h>
#include <hip/hip_bf16.h>
#include <math.h>

// Cosine attention, n=8, L=S=2048, d=v=64.
// out0 = softmax((q^·k^T)/8) @ V  [8,2048,64]; out1 = softmax scores [8,2048,2048]
// |score| <= 1/8 (unit vectors) -> exp in [0.88,1.13] -> no max subtraction.
// Normalization linear -> PV on unnormalized exp, scaled at end.
// R4 post-mortem: limiter is wave concurrency (16 waves/CU), not barriers.
// v3: 512-thr blocks (8 waves, strip=256), launch_bounds(512,8) -> VGPR<=64 ->
// 32 waves/CU; mask packing folded into the prologue (pack_mask kernel dropped);
// LDS exactly 40KB -> 4 blocks/CU; O-combine reuses dead e-bounce region.

typedef __bf16 bf16x8 __attribute__((ext_vector_type(8)));
typedef __bf16 bf16x4 __attribute__((ext_vector_type(4)));
typedef float f32x4 __attribute__((ext_vector_type(4)));

#define NB 8
#define LL 2048
#define SS 2048
#define DD 64
#define STRIP 256  // s-cols per wave (8 waves cover 2048)

// ---- prep 1: L2-normalize Q (fold 1/8) and K rows, cast to bf16 ----
__global__ __launch_bounds__(256) void prep_norm(const float* __restrict__ q,
                                                 const float* __restrict__ k,
                                                 __bf16* __restrict__ Qb,
                                                 __bf16* __restrict__ Kb) {
  int w = threadIdx.x >> 6, lane = threadIdx.x & 63;
  int r = blockIdx.x * 4 + w;
  const float* src;
  __bf16* dst;
  float extra;
  if (r < NB * LL) {
    src = q + (size_t)r * DD;
    dst = Qb + (size_t)r * DD;
    extra = 0.125f;
  } else {
    int rk = r - NB * LL;
    src = k + (size_t)rk * DD;
    dst = Kb + (size_t)rk * DD;
    extra = 1.0f;
  }
  float x = src[lane];
  float ss = x * x;
  ss += __shfl_xor(ss, 1);
  ss += __shfl_xor(ss, 2);
  ss += __shfl_xor(ss, 4);
  ss += __shfl_xor(ss, 8);
  ss += __shfl_xor(ss, 16);
  ss += __shfl_xor(ss, 32);
  float nrm = sqrtf(ss);
  float sc = extra / fmaxf(nrm, 1e-12f);
  dst[lane] = (__bf16)(x * sc);
}

// ---- prep 2: V [n][s][v] f32 -> Vt [n][v][s] bf16 ----
__global__ __launch_bounds__(256) void prep_vt(const float* __restrict__ v,
                                               __bf16* __restrict__ Vt) {
  __shared__ __bf16 tile[64][72];
  int n = blockIdx.y;
  int s0 = blockIdx.x * 64;
  int t = threadIdx.x;
#pragma unroll
  for (int it = 0; it < 4; ++it) {
    int idx = t + it * 256;
    int s = idx >> 4, c = idx & 15;
    float4 f = *(const float4*)(v + ((size_t)(n * SS + s0 + s)) * DD + c * 4);
    tile[s][c * 4 + 0] = (__bf16)f.x;
    tile[s][c * 4 + 1] = (__bf16)f.y;
    tile[s][c * 4 + 2] = (__bf16)f.z;
    tile[s][c * 4 + 3] = (__bf16)f.w;
  }
  __syncthreads();
#pragma unroll
  for (int it = 0; it < 4; ++it) {
    int idx = t + it * 256;
    int vv = idx >> 4, c = idx & 15;
    bf16x4 o;
    o[0] = tile[c * 4 + 0][vv];
    o[1] = tile[c * 4 + 1][vv];
    o[2] = tile[c * 4 + 2][vv];
    o[3] = tile[c * 4 + 3][vv];
    *(bf16x4*)(Vt + ((size_t)(n * DD + vv)) * SS + s0 + c * 4) = o;
  }
}

// ---- main v3: 16 L-rows/block; 8 waves; wave w owns s-strip [256w,256w+256) ----
// LDS map (40960 B exactly -> 4 blocks/CU):
//   [0,36864)      e_lds[8][2][16][72] bf16  (wave-private C/D->A bounce, dbuf)
//     after pass A this region is reused as:
//       [0,32768)      o_slot[8][16][64] f32 (per-wave O partials)
//       [32768,33280)  rs_lds[8][16] f32     (per-wave rowsum partials)
//   [36864,40960)  bm_t[64][16] u32 (bitmask: word w covers cols 32w..32w+31)
__global__ __launch_bounds__(512, 8) void attn_main(const __bf16* __restrict__ Qb,
                                                    const __bf16* __restrict__ Kb,
                                                    const __bf16* __restrict__ Vt,
                                                    const int* __restrict__ mask,
                                                    float* __restrict__ out_val,
                                                    float* __restrict__ out_score) {
  __shared__ char smem[40960];
  __bf16(*e_lds)[2][16][72] = (__bf16(*)[2][16][72])smem;
  unsigned(*bm_t)[16] = (unsigned(*)[16])(smem + 36864);
  float(*o_slot)[16][64] = (float(*)[16][64])smem;     // alias, valid after pass A
  float(*rs_lds)[16] = (float(*)[16])(smem + 32768);   // alias, valid after pass A

  const int n = blockIdx.y;
  const int l0 = blockIdx.x * 16;
  const int t = threadIdx.x;
  const int w = t >> 6;
  const int lane = t & 63;
  const int m16 = lane & 15;   // MFMA A row / B col / C col
  const int quad = lane >> 4;  // C/D row group

  // --- prologue: ballot this block's mask (16 rows x 2048 int32) into bits ---
  // wave w packs rows 2w, 2w+1; 8 outstanding loads per batch for MLP.
  {
#pragma unroll
    for (int rr = 0; rr < 2; ++rr) {
      const int row = 2 * w + rr;
      const int* mrow = mask + (size_t)(n * LL + l0 + row) * SS;
      for (int sb = 0; sb < 32; sb += 8) {
        int mv[8];
#pragma unroll
        for (int j = 0; j < 8; ++j) mv[j] = mrow[(sb + j) * 64 + lane];
#pragma unroll
        for (int j = 0; j < 8; ++j) {
          unsigned long long b = __ballot(mv[j] != 0);
          if (lane == 0) {
            bm_t[2 * (sb + j)][row] = (unsigned)b;
            bm_t[2 * (sb + j) + 1][row] = (unsigned)(b >> 32);
          }
        }
      }
    }
  }

  // Q A-frags: A[m=m16][k=quad*8+j], two k-steps of 32
  const __bf16* qrow = Qb + ((size_t)(n * LL + l0 + m16)) * DD;
  bf16x8 aq0 = *(const bf16x8*)(qrow + quad * 8);
  bf16x8 aq1 = *(const bf16x8*)(qrow + 32 + quad * 8);

  const __bf16* kbase = Kb + (size_t)n * SS * DD;
  const __bf16* vbase = Vt + (size_t)n * DD * SS;
  const size_t mrow_base = ((size_t)(n * LL + l0)) * SS;
  const int sbase = w * STRIP;

  f32x4 acc_o[4] = {{0.f, 0.f, 0.f, 0.f}, {0.f, 0.f, 0.f, 0.f},
                    {0.f, 0.f, 0.f, 0.f}, {0.f, 0.f, 0.f, 0.f}};
  float rsum[4] = {0.f, 0.f, 0.f, 0.f};

  __syncthreads();  // bm_t ready

  // ================= pass A (barrier-free hot loop) =================
  for (int c = 0; c < STRIP / 64; ++c) {
    const int s0 = sbase + c * 64;
    const int bw = s0 >> 5;
    const uint4 mw0 = *(const uint4*)&bm_t[bw][quad * 4];      // rows quad*4..+3
    const uint4 mw1 = *(const uint4*)&bm_t[bw + 1][quad * 4];
#pragma unroll
    for (int ct = 0; ct < 4; ++ct) {
      const __bf16* krow = kbase + (size_t)(s0 + ct * 16 + m16) * DD;
      bf16x8 kb0 = *(const bf16x8*)(krow + quad * 8);
      bf16x8 kb1 = *(const bf16x8*)(krow + 32 + quad * 8);
      f32x4 a = {0.f, 0.f, 0.f, 0.f};
      a = __builtin_amdgcn_mfma_f32_16x16x32_bf16(aq0, kb0, a, 0, 0, 0);
      a = __builtin_amdgcn_mfma_f32_16x16x32_bf16(aq1, kb1, a, 0, 0, 0);
      const unsigned sh = (unsigned)((ct * 16 + m16) & 31);
#pragma unroll
      for (int r = 0; r < 4; ++r) {
        unsigned wd = (ct < 2) ? (&mw0.x)[r] : (&mw1.x)[r];
        float e = ((wd >> sh) & 1u) ? __expf(a[r]) : 0.0f;
        rsum[r] += e;
        e_lds[w][c & 1][quad * 4 + r][ct * 16 + m16] = (__bf16)e;
      }
    }
    // PV: O[16x64] += E[16x64] @ V[64x64]; A from wave-private LDS, B from Vt
    bf16x8 ae0 = *(const bf16x8*)(&e_lds[w][c & 1][m16][quad * 8]);
    bf16x8 ae1 = *(const bf16x8*)(&e_lds[w][c & 1][m16][32 + quad * 8]);
#pragma unroll
    for (int vt = 0; vt < 4; ++vt) {
      const __bf16* vrow = vbase + (size_t)(vt * 16 + m16) * SS + s0;
      bf16x8 vb0 = *(const bf16x8*)(vrow + quad * 8);
      bf16x8 vb1 = *(const bf16x8*)(vrow + 32 + quad * 8);
      acc_o[vt] = __builtin_amdgcn_mfma_f32_16x16x32_bf16(ae0, vb0, acc_o[vt], 0, 0, 0);
      acc_o[vt] = __builtin_amdgcn_mfma_f32_16x16x32_bf16(ae1, vb1, acc_o[vt], 0, 0, 0);
    }
  }

  // --- per-wave rowsum over its strip (reduce across m16 lanes) ---
#pragma unroll
  for (int r = 0; r < 4; ++r) {
    float s = rsum[r];
    s += __shfl_xor(s, 1);
    s += __shfl_xor(s, 2);
    s += __shfl_xor(s, 4);
    s += __shfl_xor(s, 8);
    rsum[r] = s;
  }

  __syncthreads();  // ALL waves done with e_lds -> region reusable for o_slot/rs

  // --- publish per-wave partials ---
#pragma unroll
  for (int vt = 0; vt < 4; ++vt)
#pragma unroll
    for (int r = 0; r < 4; ++r) o_slot[w][quad * 4 + r][vt * 16 + m16] = acc_o[vt][r];
  if (m16 == 0) {
#pragma unroll
    for (int r = 0; r < 4; ++r) rs_lds[w][quad * 4 + r] = rsum[r];
  }
  __syncthreads();

  // --- combine 8 partials, write out_val (512 threads x 2 elements) ---
#pragma unroll
  for (int e = 0; e < 2; ++e) {
    int el = t + e * 512;
    int row = el >> 6, col = el & 63;
    float o = 0.f, s = 0.f;
#pragma unroll
    for (int j = 0; j < 8; ++j) {
      o += o_slot[j][row][col];
      s += rs_lds[j][row];
    }
    out_val[((size_t)(n * LL + l0 + row)) * DD + col] = o / s;
  }

  // --- inv per this thread's C/D rows for pass B ---
  float inv[4];
#pragma unroll
  for (int r = 0; r < 4; ++r) {
    int row = quad * 4 + r;
    float s = 0.f;
#pragma unroll
    for (int j = 0; j < 8; ++j) s += rs_lds[j][row];
    inv[r] = 1.0f / s;
  }

  // ============ pass B: recompute scores, scale, store (barrier-free) ========
  for (int c = 0; c < STRIP / 64; ++c) {
    const int s0 = sbase + c * 64;
    const int bw = s0 >> 5;
    const uint4 mw0 = *(const uint4*)&bm_t[bw][quad * 4];
    const uint4 mw1 = *(const uint4*)&bm_t[bw + 1][quad * 4];
#pragma unroll
    for (int ct = 0; ct < 4; ++ct) {
      const __bf16* krow = kbase + (size_t)(s0 + ct * 16 + m16) * DD;
      bf16x8 kb0 = *(const bf16x8*)(krow + quad * 8);
      bf16x8 kb1 = *(const bf16x8*)(krow + 32 + quad * 8);
      f32x4 a = {0.f, 0.f, 0.f, 0.f};
      a = __builtin_amdgcn_mfma_f32_16x16x32_bf16(aq0, kb0, a, 0, 0, 0);
      a = __builtin_amdgcn_mfma_f32_16x16x32_bf16(aq1, kb1, a, 0, 0, 0);
      const unsigned sh = (unsigned)((ct * 16 + m16) & 31);
#pragma unroll
      for (int r = 0; r < 4; ++r) {
        unsigned wd = (ct < 2) ? (&mw0.x)[r] : (&mw1.x)[r];
        float val = ((wd >> sh) & 1u) ? __expf(a[r]) * inv[r] : 0.0f;
        out_score[mrow_base + (size_t)(quad * 4 + r) * SS + s0 + ct * 16 + m16] = val;
      }
    }
  }
}

extern "C" void kernel_launch(void* const* d_in, const int* in_sizes, int n_in,
                              void* d_out, int out_size, void* d_ws, size_t ws_size,
                              hipStream_t stream) {
  const float* q = (const float*)d_in[0];
  const float* k = (const float*)d_in[1];
  const float* v = (const float*)d_in[2];
  const int* mask = (const int*)d_in[3];  // bool materialized as int32

  float* out_val = (float*)d_out;                     // [8,2048,64]
  float* out_score = out_val + (size_t)NB * LL * DD;  // [8,2048,2048]

  __bf16* Qb = (__bf16*)d_ws;                 // 2 MB
  __bf16* Kb = Qb + (size_t)NB * LL * DD;     // 2 MB
  __bf16* Vt = Kb + (size_t)NB * SS * DD;     // 2 MB

  prep_norm<<<dim3((NB * LL * 2) / 4), dim3(256), 0, stream>>>(q, k, Qb, Kb);
  prep_vt<<<dim3(SS / 64, NB), dim3(256), 0, stream>>>(v, Vt);
  attn_main<<<dim3(LL / 16, NB), dim3(512), 0, stream>>>(Qb, Kb, Vt, mask,
                                                         out_val, out_score);
}